// Round 1
// baseline (309.784 us; speedup 1.0000x reference)
//
#include <hip/hip_runtime.h>

#define D 128
#define TN 24   // GEMM: nodes per block

// ---------------- copy: h = x (EPS=0 so (1+eps)*x = x) ----------------
__global__ __launch_bounds__(256) void gin_copy(const float* __restrict__ x,
                                                float* __restrict__ h, int n4) {
    int stride = gridDim.x * 256;
    for (int i = blockIdx.x * 256 + threadIdx.x; i < n4; i += stride) {
        ((float4*)h)[i] = ((const float4*)x)[i];
    }
}

// ---------------- scatter: h[dst] += x[src], one thread per (edge, feat) ----------------
__global__ __launch_bounds__(256) void gin_scatter(const float* __restrict__ x,
                                                   const int* __restrict__ src,
                                                   const int* __restrict__ dst,
                                                   float* __restrict__ h,
                                                   int nedges) {
    long long gid = (long long)blockIdx.x * 256 + threadIdx.x;
    long long total = (long long)nedges * D;
    if (gid >= total) return;
    int e = (int)(gid >> 7);      // edge id
    int d = (int)(gid & (D - 1)); // feature id
    int s = src[e];
    int t = dst[e];
    atomicAdd(h + (size_t)t * D + d, x[(size_t)s * D + d]);
}

// ---------------- in-place GEMM: h <- h @ W^T + b ----------------
// W is [128][128] row-major (out, in). Wt in LDS padded to 132 floats/row:
//   - staging writes: consecutive lanes write stride-132 words -> 8 banks, 8-way, once per block
//   - inner-loop reads: contiguous 512B per k across lanes, 16B-aligned, conflict-free
__global__ __launch_bounds__(256) void gin_gemm(float* __restrict__ h,
                                                const float* __restrict__ W,
                                                const float* __restrict__ b,
                                                int nrows) {
    __shared__ float Wt[D * 132];
    __shared__ float hl[TN * D];

    int tid = threadIdx.x;

    // stage W transposed (coalesced global read)
    for (int i = tid; i < D * D; i += 256) {
        int o = i >> 7;         // out col
        int d = i & (D - 1);    // in dim
        Wt[d * 132 + o] = W[i];
    }

    int base = blockIdx.x * TN;
    int rows = nrows - base;
    if (rows > TN) rows = TN;

    // stage h tile (float4, coalesced)
    {
        const float4* hsrc = (const float4*)(h + (size_t)base * D);
        float4* hl4 = (float4*)hl;
        int n4 = rows * (D / 4);
        for (int i = tid; i < n4; i += 256) hl4[i] = hsrc[i];
    }
    __syncthreads();

    int cg = tid & 31;   // col group: cols cg*4 .. cg*4+3
    int ng = tid >> 5;   // node group: rows ng*3 .. ng*3+2

    float acc[3][4];
#pragma unroll
    for (int i = 0; i < 3; i++)
#pragma unroll
        for (int j = 0; j < 4; j++) acc[i][j] = 0.0f;

    for (int k = 0; k < D; k += 4) {
        float4 hv[3];
#pragma unroll
        for (int i = 0; i < 3; i++)
            hv[i] = *(const float4*)&hl[(ng * 3 + i) * D + k];
#pragma unroll
        for (int kk = 0; kk < 4; kk++) {
            float4 wv = *(const float4*)&Wt[(k + kk) * 132 + cg * 4];
            const float* wf = (const float*)&wv;
#pragma unroll
            for (int i = 0; i < 3; i++) {
                float hs = ((const float*)&hv[i])[kk];
#pragma unroll
                for (int j = 0; j < 4; j++) acc[i][j] += hs * wf[j];
            }
        }
    }

    float4 bv = *(const float4*)(b + cg * 4);
    const float* bf = (const float*)&bv;

#pragma unroll
    for (int i = 0; i < 3; i++) {
        int row = ng * 3 + i;
        if (row < rows) {
            float4 ov;
            ((float*)&ov)[0] = acc[i][0] + bf[0];
            ((float*)&ov)[1] = acc[i][1] + bf[1];
            ((float*)&ov)[2] = acc[i][2] + bf[2];
            ((float*)&ov)[3] = acc[i][3] + bf[3];
            *(float4*)&h[(size_t)(base + row) * D + cg * 4] = ov;
        }
    }
}

extern "C" void kernel_launch(void* const* d_in, const int* in_sizes, int n_in,
                              void* d_out, int out_size, void* d_ws, size_t ws_size,
                              hipStream_t stream) {
    const float* x  = (const float*)d_in[0];
    const int*   ei = (const int*)d_in[1];   // [2][E] int (harness converts integer inputs to int32)
    const float* W  = (const float*)d_in[2];
    const float* bb = (const float*)d_in[3];
    float* out = (float*)d_out;

    int nnodes = in_sizes[0] / D;
    int nedges = in_sizes[1] / 2;
    const int* src = ei;
    const int* dst = ei + nedges;

    // 1) out = x
    int n4 = nnodes * (D / 4);
    gin_copy<<<2048, 256, 0, stream>>>(x, out, n4);

    // 2) out[dst] += x[src]
    long long total = (long long)nedges * D;
    int sblocks = (int)((total + 255) / 256);
    gin_scatter<<<sblocks, 256, 0, stream>>>(x, src, dst, out, nedges);

    // 3) out = out @ W^T + b  (in place)
    int gblocks = (nnodes + TN - 1) / TN;
    gin_gemm<<<gblocks, 256, 0, stream>>>(out, W, bb, nnodes);
}

// Round 2
// 182.770 us; speedup vs baseline: 1.6949x; 1.6949x over previous
//
#include <hip/hip_runtime.h>

#define D 128
#define TN 24   // GEMM: nodes per block

// ---------------- CSR build ----------------

// deg[dst]++ per edge
__global__ __launch_bounds__(256) void gin_hist(const int* __restrict__ dst,
                                                int* __restrict__ deg, int nedges) {
    int e = blockIdx.x * 256 + threadIdx.x;
    if (e < nedges) atomicAdd(&deg[dst[e]], 1);
}

// per-block sums of deg (256 per block)
__global__ __launch_bounds__(256) void gin_bsum(const int* __restrict__ deg,
                                                int* __restrict__ bsum, int n) {
    __shared__ int sh[256];
    int i = blockIdx.x * 256 + threadIdx.x;
    int v = (i < n) ? deg[i] : 0;
    sh[threadIdx.x] = v;
    __syncthreads();
    for (int off = 128; off > 0; off >>= 1) {
        if (threadIdx.x < off) sh[threadIdx.x] += sh[threadIdx.x + off];
        __syncthreads();
    }
    if (threadIdx.x == 0) bsum[blockIdx.x] = sh[0];
}

// exclusive scan of bsum (nb <= 256), one block; also writes rowptr[n] = total
__global__ __launch_bounds__(256) void gin_bscan(const int* __restrict__ bsum,
                                                 int* __restrict__ boff,
                                                 int* __restrict__ rowptr,
                                                 int nb, int n) {
    __shared__ int sh[256];
    int i = threadIdx.x;
    int v = (i < nb) ? bsum[i] : 0;
    sh[i] = v;
    __syncthreads();
    for (int off = 1; off < 256; off <<= 1) {
        int t = (i >= off) ? sh[i - off] : 0;
        __syncthreads();
        sh[i] += t;
        __syncthreads();
    }
    if (i < nb) boff[i] = sh[i] - v;          // exclusive
    if (i == 255) rowptr[n] = sh[255];        // total edge count
}

// per-block exclusive scan of deg + boff -> rowptr, cursor
__global__ __launch_bounds__(256) void gin_scan(const int* __restrict__ deg,
                                                const int* __restrict__ boff,
                                                int* __restrict__ rowptr,
                                                int* __restrict__ cursor, int n) {
    __shared__ int sh[256];
    int i = blockIdx.x * 256 + threadIdx.x;
    int v = (i < n) ? deg[i] : 0;
    sh[threadIdx.x] = v;
    __syncthreads();
    for (int off = 1; off < 256; off <<= 1) {
        int t = (threadIdx.x >= off) ? sh[threadIdx.x - off] : 0;
        __syncthreads();
        sh[threadIdx.x] += t;
        __syncthreads();
    }
    if (i < n) {
        int ex = boff[blockIdx.x] + sh[threadIdx.x] - v;
        rowptr[i] = ex;
        cursor[i] = ex;
    }
}

// scatter edges into CSR buckets
__global__ __launch_bounds__(256) void gin_fill(const int* __restrict__ src,
                                                const int* __restrict__ dst,
                                                int* __restrict__ cursor,
                                                int* __restrict__ csr_src, int nedges) {
    int e = blockIdx.x * 256 + threadIdx.x;
    if (e < nedges) {
        int pos = atomicAdd(&cursor[dst[e]], 1);
        csr_src[pos] = src[e];
    }
}

// ---------------- gather: h[i] = x[i] + sum_{e in csr[i]} x[csr_src[e]] ----------------
// one wave per node; lane handles a float2 (8B) slice of the 512B row
__global__ __launch_bounds__(256) void gin_gather(const float* __restrict__ x,
                                                  const int* __restrict__ rowptr,
                                                  const int* __restrict__ csr_src,
                                                  float* __restrict__ h, int nnodes) {
    int wave = (blockIdx.x * 256 + threadIdx.x) >> 6;
    int lane = threadIdx.x & 63;
    if (wave >= nnodes) return;

    int beg = rowptr[wave];
    int end = rowptr[wave + 1];

    float2 acc = *(const float2*)&x[(size_t)wave * D + lane * 2];  // self term (eps=0)

    int s = (beg < end) ? csr_src[beg] : 0;
    for (int e = beg; e < end; ++e) {
        int snext = (e + 1 < end) ? csr_src[e + 1] : 0;   // prefetch next index
        float2 v = *(const float2*)&x[(size_t)s * D + lane * 2];
        acc.x += v.x;
        acc.y += v.y;
        s = snext;
    }
    *(float2*)&h[(size_t)wave * D + lane * 2] = acc;
}

// ---------------- in-place GEMM: h <- h @ W^T + b ----------------
__global__ __launch_bounds__(256) void gin_gemm(float* __restrict__ h,
                                                const float* __restrict__ W,
                                                const float* __restrict__ b,
                                                int nrows) {
    __shared__ float Wt[D * 132];
    __shared__ float hl[TN * D];

    int tid = threadIdx.x;

    for (int i = tid; i < D * D; i += 256) {
        int o = i >> 7;
        int d = i & (D - 1);
        Wt[d * 132 + o] = W[i];
    }

    int base = blockIdx.x * TN;
    int rows = nrows - base;
    if (rows > TN) rows = TN;

    {
        const float4* hsrc = (const float4*)(h + (size_t)base * D);
        float4* hl4 = (float4*)hl;
        int n4 = rows * (D / 4);
        for (int i = tid; i < n4; i += 256) hl4[i] = hsrc[i];
    }
    __syncthreads();

    int cg = tid & 31;
    int ng = tid >> 5;

    float acc[3][4];
#pragma unroll
    for (int i = 0; i < 3; i++)
#pragma unroll
        for (int j = 0; j < 4; j++) acc[i][j] = 0.0f;

    for (int k = 0; k < D; k += 4) {
        float4 hv[3];
#pragma unroll
        for (int i = 0; i < 3; i++)
            hv[i] = *(const float4*)&hl[(ng * 3 + i) * D + k];
#pragma unroll
        for (int kk = 0; kk < 4; kk++) {
            float4 wv = *(const float4*)&Wt[(k + kk) * 132 + cg * 4];
            const float* wf = (const float*)&wv;
#pragma unroll
            for (int i = 0; i < 3; i++) {
                float hs = ((const float*)&hv[i])[kk];
#pragma unroll
                for (int j = 0; j < 4; j++) acc[i][j] += hs * wf[j];
            }
        }
    }

    float4 bv = *(const float4*)(b + cg * 4);
    const float* bf = (const float*)&bv;

#pragma unroll
    for (int i = 0; i < 3; i++) {
        int row = ng * 3 + i;
        if (row < rows) {
            float4 ov;
            ((float*)&ov)[0] = acc[i][0] + bf[0];
            ((float*)&ov)[1] = acc[i][1] + bf[1];
            ((float*)&ov)[2] = acc[i][2] + bf[2];
            ((float*)&ov)[3] = acc[i][3] + bf[3];
            *(float4*)&h[(size_t)(base + row) * D + cg * 4] = ov;
        }
    }
}

extern "C" void kernel_launch(void* const* d_in, const int* in_sizes, int n_in,
                              void* d_out, int out_size, void* d_ws, size_t ws_size,
                              hipStream_t stream) {
    const float* x  = (const float*)d_in[0];
    const int*   ei = (const int*)d_in[1];
    const float* W  = (const float*)d_in[2];
    const float* bb = (const float*)d_in[3];
    float* out = (float*)d_out;

    int nnodes = in_sizes[0] / D;
    int nedges = in_sizes[1] / 2;
    const int* src = ei;
    const int* dst = ei + nedges;

    int nb = (nnodes + 255) / 256;          // scan blocks (<= 256 for nnodes <= 65536)
    int npad = nb * 256;

    // workspace layout (ints)
    int* deg     = (int*)d_ws;              // [npad]
    int* rowptr  = deg + npad;              // [nnodes + 1]
    int* cursor  = rowptr + nnodes + 1;     // [npad]
    int* bsum    = cursor + npad;           // [nb]
    int* boff    = bsum + 256;              // [nb]
    int* csr_src = boff + 256;              // [nedges]

    hipMemsetAsync(deg, 0, (size_t)npad * sizeof(int), stream);

    int eb = (nedges + 255) / 256;
    gin_hist<<<eb, 256, 0, stream>>>(dst, deg, nedges);
    gin_bsum<<<nb, 256, 0, stream>>>(deg, bsum, nnodes);
    gin_bscan<<<1, 256, 0, stream>>>(bsum, boff, rowptr, nb, nnodes);
    gin_scan<<<nb, 256, 0, stream>>>(deg, boff, rowptr, cursor, nnodes);
    gin_fill<<<eb, 256, 0, stream>>>(src, dst, cursor, csr_src, nedges);

    // gather: one wave per node
    int gb = (nnodes * 64 + 255) / 256;
    gin_gather<<<gb, 256, 0, stream>>>(x, rowptr, csr_src, out, nnodes);

    // GEMM in place on d_out
    int gblocks = (nnodes + TN - 1) / TN;
    gin_gemm<<<gblocks, 256, 0, stream>>>(out, W, bb, nnodes);
}

// Round 3
// 137.578 us; speedup vs baseline: 2.2517x; 1.3285x over previous
//
#include <hip/hip_runtime.h>

#define D 128
#define TN 24     // old fp32 GEMM: nodes per block (fallback path)
#define LDW 136   // padded LDS row (bf16 elems): +8 → 2-way bank aliasing (free)

typedef __attribute__((ext_vector_type(8))) short bf16x8;
typedef __attribute__((ext_vector_type(4))) float f32x4;

static __device__ __forceinline__ ushort f2bf(float f) {
    union { float f; unsigned u; } c; c.f = f;
    unsigned u = c.u;
    return (ushort)((u + 0x7fffu + ((u >> 16) & 1u)) >> 16);  // RNE
}
static __device__ __forceinline__ float bflo(unsigned v) {
    union { unsigned u; float f; } c; c.u = v << 16; return c.f;
}
static __device__ __forceinline__ float bfhi(unsigned v) {
    union { unsigned u; float f; } c; c.u = v & 0xffff0000u; return c.f;
}

// ---------------- x (fp32) -> xb (bf16) ----------------
__global__ __launch_bounds__(256) void gin_cvt(const float* __restrict__ x,
                                               ushort* __restrict__ xb, int n4) {
    int stride = gridDim.x * 256;
    for (int i = blockIdx.x * 256 + threadIdx.x; i < n4; i += stride) {
        float4 v = ((const float4*)x)[i];
        ushort4 o;
        o.x = f2bf(v.x); o.y = f2bf(v.y); o.z = f2bf(v.z); o.w = f2bf(v.w);
        ((ushort4*)xb)[i] = o;
    }
}

// ---------------- CSR build ----------------
__global__ __launch_bounds__(256) void gin_hist(const int* __restrict__ dst,
                                                int* __restrict__ deg, int nedges) {
    int e = blockIdx.x * 256 + threadIdx.x;
    if (e < nedges) atomicAdd(&deg[dst[e]], 1);
}

__global__ __launch_bounds__(256) void gin_bsum(const int* __restrict__ deg,
                                                int* __restrict__ bsum, int n) {
    __shared__ int sh[256];
    int i = blockIdx.x * 256 + threadIdx.x;
    int v = (i < n) ? deg[i] : 0;
    sh[threadIdx.x] = v;
    __syncthreads();
    for (int off = 128; off > 0; off >>= 1) {
        if (threadIdx.x < off) sh[threadIdx.x] += sh[threadIdx.x + off];
        __syncthreads();
    }
    if (threadIdx.x == 0) bsum[blockIdx.x] = sh[0];
}

__global__ __launch_bounds__(256) void gin_bscan(const int* __restrict__ bsum,
                                                 int* __restrict__ boff,
                                                 int* __restrict__ rowptr,
                                                 int nb, int n) {
    __shared__ int sh[256];
    int i = threadIdx.x;
    int v = (i < nb) ? bsum[i] : 0;
    sh[i] = v;
    __syncthreads();
    for (int off = 1; off < 256; off <<= 1) {
        int t = (i >= off) ? sh[i - off] : 0;
        __syncthreads();
        sh[i] += t;
        __syncthreads();
    }
    if (i < nb) boff[i] = sh[i] - v;
    if (i == 255) rowptr[n] = sh[255];
}

__global__ __launch_bounds__(256) void gin_scan(const int* __restrict__ deg,
                                                const int* __restrict__ boff,
                                                int* __restrict__ rowptr,
                                                int* __restrict__ cursor, int n) {
    __shared__ int sh[256];
    int i = blockIdx.x * 256 + threadIdx.x;
    int v = (i < n) ? deg[i] : 0;
    sh[threadIdx.x] = v;
    __syncthreads();
    for (int off = 1; off < 256; off <<= 1) {
        int t = (threadIdx.x >= off) ? sh[threadIdx.x - off] : 0;
        __syncthreads();
        sh[threadIdx.x] += t;
        __syncthreads();
    }
    if (i < n) {
        int ex = boff[blockIdx.x] + sh[threadIdx.x] - v;
        rowptr[i] = ex;
        cursor[i] = ex;
    }
}

__global__ __launch_bounds__(256) void gin_fill(const int* __restrict__ src,
                                                const int* __restrict__ dst,
                                                int* __restrict__ cursor,
                                                int* __restrict__ csr_src, int nedges) {
    int e = blockIdx.x * 256 + threadIdx.x;
    if (e < nedges) {
        int pos = atomicAdd(&cursor[dst[e]], 1);
        csr_src[pos] = src[e];
    }
}

// ---------------- gather (bf16): hb[i] = bf16( x[i] + sum_e xb[csr_src[e]] ) ----------------
// one wave per node; lane owns 4B (2 bf16) of the 256B row; edge loop unrolled x4 for MLP
__global__ __launch_bounds__(256) void gin_gather_bf(const float* __restrict__ x,
                                                     const ushort* __restrict__ xb,
                                                     const int* __restrict__ rowptr,
                                                     const int* __restrict__ csr_src,
                                                     ushort* __restrict__ hb, int nnodes) {
    int wave = blockIdx.x * 4 + (threadIdx.x >> 6);
    int lane = threadIdx.x & 63;
    if (wave >= nnodes) return;

    int beg = rowptr[wave];
    int end = rowptr[wave + 1];

    float2 acc = *(const float2*)&x[(size_t)wave * D + lane * 2];  // self term fp32 (eps=0)
    const unsigned* xbu = (const unsigned*)xb;  // 1 uint = 2 bf16

    int e = beg;
    for (; e + 4 <= end; e += 4) {
        int s0 = csr_src[e];
        int s1 = csr_src[e + 1];
        int s2 = csr_src[e + 2];
        int s3 = csr_src[e + 3];
        unsigned v0 = xbu[(size_t)s0 * 64 + lane];
        unsigned v1 = xbu[(size_t)s1 * 64 + lane];
        unsigned v2 = xbu[(size_t)s2 * 64 + lane];
        unsigned v3 = xbu[(size_t)s3 * 64 + lane];
        acc.x += (bflo(v0) + bflo(v1)) + (bflo(v2) + bflo(v3));
        acc.y += (bfhi(v0) + bfhi(v1)) + (bfhi(v2) + bfhi(v3));
    }
    for (; e < end; ++e) {
        unsigned v = xbu[(size_t)csr_src[e] * 64 + lane];
        acc.x += bflo(v);
        acc.y += bfhi(v);
    }
    unsigned o = (unsigned)f2bf(acc.x) | ((unsigned)f2bf(acc.y) << 16);
    ((unsigned*)hb)[(size_t)wave * 64 + lane] = o;
}

// ---------------- MFMA GEMM: out = hb @ W^T + b (bf16 in, fp32 out) ----------------
// block = 256 thr = 4 waves (2x2), BM=64, N=128, K=128; 16x16x32 bf16 MFMA
__global__ __launch_bounds__(256) void gin_gemm_mfma(const ushort* __restrict__ hb,
                                                     const float* __restrict__ W,
                                                     const float* __restrict__ bias,
                                                     float* __restrict__ out, int nrows) {
    __shared__ ushort Wl[D * LDW];   // Wl[o][k] = bf16(W[o][k]) — B operand, k contiguous
    __shared__ ushort Al[64 * LDW];  // Al[m][k] = hb tile

    int tid = threadIdx.x;

    // stage W fp32->bf16 (4096 float4 chunks)
    for (int i = tid; i < D * D / 4; i += 256) {
        float4 v = ((const float4*)W)[i];
        int row = i >> 5;          // (i*4)/128
        int col = (i & 31) * 4;
        ushort4 o;
        o.x = f2bf(v.x); o.y = f2bf(v.y); o.z = f2bf(v.z); o.w = f2bf(v.w);
        *(ushort4*)&Wl[row * LDW + col] = o;
    }

    int base = blockIdx.x * 64;
    // stage A tile: 64 rows x 256B = 1024 x 16B chunks
    for (int j = tid; j < 1024; j += 256) {
        int row = j >> 4;
        int col = (j & 15) * 8;
        uint4 v = make_uint4(0, 0, 0, 0);
        if (base + row < nrows) v = *(const uint4*)&hb[(size_t)(base + row) * D + col];
        *(uint4*)&Al[row * LDW + col] = v;
    }
    __syncthreads();

    int w = tid >> 6, l = tid & 63;
    int wr = w >> 1, wc = w & 1;     // 2x2 wave grid: 32 rows x 64 cols per wave
    int lr = l & 15, hi = l >> 4;

    f32x4 acc[2][4];
#pragma unroll
    for (int m = 0; m < 2; m++)
#pragma unroll
        for (int t = 0; t < 4; t++) acc[m][t] = (f32x4)0.0f;

#pragma unroll
    for (int ks = 0; ks < 4; ks++) {
        int kof = ks * 32 + hi * 8;
        bf16x8 a0 = *(bf16x8*)&Al[(wr * 32 + lr) * LDW + kof];
        bf16x8 a1 = *(bf16x8*)&Al[(wr * 32 + 16 + lr) * LDW + kof];
#pragma unroll
        for (int t = 0; t < 4; t++) {
            bf16x8 bm = *(bf16x8*)&Wl[(wc * 64 + t * 16 + lr) * LDW + kof];
            acc[0][t] = __builtin_amdgcn_mfma_f32_16x16x32_bf16(a0, bm, acc[0][t], 0, 0, 0);
            acc[1][t] = __builtin_amdgcn_mfma_f32_16x16x32_bf16(a1, bm, acc[1][t], 0, 0, 0);
        }
    }

    // C/D layout (m89-verified): col = lane&15, row = (lane>>4)*4 + reg
#pragma unroll
    for (int m = 0; m < 2; m++) {
#pragma unroll
        for (int t = 0; t < 4; t++) {
            int col = wc * 64 + t * 16 + lr;
            float bv = bias[col];
#pragma unroll
            for (int r = 0; r < 4; r++) {
                int row = base + wr * 32 + m * 16 + hi * 4 + r;
                if (row < nrows) out[(size_t)row * D + col] = acc[m][t][r] + bv;
            }
        }
    }
}

// ---------------- fallback fp32 path (R2-proven) ----------------
__global__ __launch_bounds__(256) void gin_gather(const float* __restrict__ x,
                                                  const int* __restrict__ rowptr,
                                                  const int* __restrict__ csr_src,
                                                  float* __restrict__ h, int nnodes) {
    int wave = (blockIdx.x * 256 + threadIdx.x) >> 6;
    int lane = threadIdx.x & 63;
    if (wave >= nnodes) return;
    int beg = rowptr[wave];
    int end = rowptr[wave + 1];
    float2 acc = *(const float2*)&x[(size_t)wave * D + lane * 2];
    int s = (beg < end) ? csr_src[beg] : 0;
    for (int e = beg; e < end; ++e) {
        int snext = (e + 1 < end) ? csr_src[e + 1] : 0;
        float2 v = *(const float2*)&x[(size_t)s * D + lane * 2];
        acc.x += v.x;
        acc.y += v.y;
        s = snext;
    }
    *(float2*)&h[(size_t)wave * D + lane * 2] = acc;
}

__global__ __launch_bounds__(256) void gin_gemm(float* __restrict__ h,
                                                const float* __restrict__ W,
                                                const float* __restrict__ b,
                                                int nrows) {
    __shared__ float Wt[D * 132];
    __shared__ float hl[TN * D];
    int tid = threadIdx.x;
    for (int i = tid; i < D * D; i += 256) {
        int o = i >> 7;
        int d = i & (D - 1);
        Wt[d * 132 + o] = W[i];
    }
    int base = blockIdx.x * TN;
    int rows = nrows - base;
    if (rows > TN) rows = TN;
    {
        const float4* hsrc = (const float4*)(h + (size_t)base * D);
        float4* hl4 = (float4*)hl;
        int n4 = rows * (D / 4);
        for (int i = tid; i < n4; i += 256) hl4[i] = hsrc[i];
    }
    __syncthreads();
    int cg = tid & 31;
    int ng = tid >> 5;
    float acc[3][4];
#pragma unroll
    for (int i = 0; i < 3; i++)
#pragma unroll
        for (int j = 0; j < 4; j++) acc[i][j] = 0.0f;
    for (int k = 0; k < D; k += 4) {
        float4 hv[3];
#pragma unroll
        for (int i = 0; i < 3; i++)
            hv[i] = *(const float4*)&hl[(ng * 3 + i) * D + k];
#pragma unroll
        for (int kk = 0; kk < 4; kk++) {
            float4 wv = *(const float4*)&Wt[(k + kk) * 132 + cg * 4];
            const float* wf = (const float*)&wv;
#pragma unroll
            for (int i = 0; i < 3; i++) {
                float hs = ((const float*)&hv[i])[kk];
#pragma unroll
                for (int j = 0; j < 4; j++) acc[i][j] += hs * wf[j];
            }
        }
    }
    float4 bv = *(const float4*)(b + cg * 4);
    const float* bf = (const float*)&bv;
#pragma unroll
    for (int i = 0; i < 3; i++) {
        int row = ng * 3 + i;
        if (row < rows) {
            float4 ov;
            ((float*)&ov)[0] = acc[i][0] + bf[0];
            ((float*)&ov)[1] = acc[i][1] + bf[1];
            ((float*)&ov)[2] = acc[i][2] + bf[2];
            ((float*)&ov)[3] = acc[i][3] + bf[3];
            *(float4*)&h[(size_t)(base + row) * D + cg * 4] = ov;
        }
    }
}

extern "C" void kernel_launch(void* const* d_in, const int* in_sizes, int n_in,
                              void* d_out, int out_size, void* d_ws, size_t ws_size,
                              hipStream_t stream) {
    const float* x  = (const float*)d_in[0];
    const int*   ei = (const int*)d_in[1];
    const float* W  = (const float*)d_in[2];
    const float* bb = (const float*)d_in[3];
    float* out = (float*)d_out;

    int nnodes = in_sizes[0] / D;
    int nedges = in_sizes[1] / 2;
    const int* src = ei;
    const int* dst = ei + nedges;

    int nb = (nnodes + 255) / 256;
    int npad = nb * 256;

    // workspace layout
    char* p = (char*)d_ws;
    int* deg     = (int*)p;  p += (size_t)npad * 4;
    int* rowptr  = (int*)p;  p += (size_t)(nnodes + 1) * 4;
    int* cursor  = (int*)p;  p += (size_t)npad * 4;
    int* bsum    = (int*)p;  p += 256 * 4;
    int* boff    = (int*)p;  p += 256 * 4;
    int* csr_src = (int*)p;  p += (size_t)nedges * 4;
    p = (char*)(((uintptr_t)p + 15) & ~(uintptr_t)15);
    ushort* xb = (ushort*)p; p += (size_t)nnodes * D * 2;
    ushort* hb = (ushort*)p; p += (size_t)nnodes * D * 2;
    size_t required = (size_t)(p - (char*)d_ws);

    hipMemsetAsync(deg, 0, (size_t)npad * sizeof(int), stream);

    int eb = (nedges + 255) / 256;
    gin_hist<<<eb, 256, 0, stream>>>(dst, deg, nedges);
    gin_bsum<<<nb, 256, 0, stream>>>(deg, bsum, nnodes);
    gin_bscan<<<1, 256, 0, stream>>>(bsum, boff, rowptr, nb, nnodes);
    gin_scan<<<nb, 256, 0, stream>>>(deg, boff, rowptr, cursor, nnodes);
    gin_fill<<<eb, 256, 0, stream>>>(src, dst, cursor, csr_src, nedges);

    if (ws_size >= required) {
        // bf16 path
        int n4 = nnodes * (D / 4);
        gin_cvt<<<2048, 256, 0, stream>>>(x, xb, n4);
        int gb = (nnodes + 3) / 4;  // 4 waves per block, 1 node per wave
        gin_gather_bf<<<gb, 256, 0, stream>>>(x, xb, rowptr, csr_src, hb, nnodes);
        int gemb = (nnodes + 63) / 64;
        gin_gemm_mfma<<<gemb, 256, 0, stream>>>(hb, W, bb, out, nnodes);
    } else {
        // fp32 fallback (R2 path)
        int gb = (nnodes * 64 + 255) / 256;
        gin_gather<<<gb, 256, 0, stream>>>(x, rowptr, csr_src, out, nnodes);
        int gblocks = (nnodes + TN - 1) / TN;
        gin_gemm<<<gblocks, 256, 0, stream>>>(out, W, bb, nnodes);
    }
}

// Round 4
// 129.598 us; speedup vs baseline: 2.3903x; 1.0616x over previous
//
#include <hip/hip_runtime.h>

#define D 128
#define LDW 136   // padded LDS row (bf16 elems): +8 → 2-way bank aliasing (free)

typedef __attribute__((ext_vector_type(8))) short bf16x8;
typedef __attribute__((ext_vector_type(4))) float f32x4;

static __device__ __forceinline__ ushort f2bf(float f) {
    union { float f; unsigned u; } c; c.f = f;
    unsigned u = c.u;
    return (ushort)((u + 0x7fffu + ((u >> 16) & 1u)) >> 16);  // RNE
}
static __device__ __forceinline__ float bflo(unsigned v) {
    union { unsigned u; float f; } c; c.u = v << 16; return c.f;
}
static __device__ __forceinline__ float bfhi(unsigned v) {
    union { unsigned u; float f; } c; c.u = v & 0xffff0000u; return c.f;
}

// ---------------- prep: deg = 0  AND  xb = bf16(x) (fused, independent outputs) ----------------
__global__ __launch_bounds__(256) void gin_prep(const float* __restrict__ x,
                                                ushort* __restrict__ xb, int n4,
                                                int* __restrict__ deg, int ndeg4) {
    int stride = gridDim.x * 256;
    int tid0 = blockIdx.x * 256 + threadIdx.x;
    for (int i = tid0; i < ndeg4; i += stride) {
        ((int4*)deg)[i] = make_int4(0, 0, 0, 0);
    }
    for (int i = tid0; i < n4; i += stride) {
        float4 v = ((const float4*)x)[i];
        ushort4 o;
        o.x = f2bf(v.x); o.y = f2bf(v.y); o.z = f2bf(v.z); o.w = f2bf(v.w);
        ((ushort4*)xb)[i] = o;
    }
}

// ---------------- CSR build ----------------
__global__ __launch_bounds__(256) void gin_hist(const int* __restrict__ dst,
                                                int* __restrict__ deg, int nedges) {
    int e = blockIdx.x * 256 + threadIdx.x;
    if (e < nedges) atomicAdd(&deg[dst[e]], 1);
}

__global__ __launch_bounds__(256) void gin_bsum(const int* __restrict__ deg,
                                                int* __restrict__ bsum, int n) {
    __shared__ int sh[256];
    int i = blockIdx.x * 256 + threadIdx.x;
    int v = (i < n) ? deg[i] : 0;
    sh[threadIdx.x] = v;
    __syncthreads();
    for (int off = 128; off > 0; off >>= 1) {
        if (threadIdx.x < off) sh[threadIdx.x] += sh[threadIdx.x + off];
        __syncthreads();
    }
    if (threadIdx.x == 0) bsum[blockIdx.x] = sh[0];
}

__global__ __launch_bounds__(256) void gin_bscan(const int* __restrict__ bsum,
                                                 int* __restrict__ boff,
                                                 int* __restrict__ rowptr,
                                                 int nb, int n) {
    __shared__ int sh[256];
    int i = threadIdx.x;
    int v = (i < nb) ? bsum[i] : 0;
    sh[i] = v;
    __syncthreads();
    for (int off = 1; off < 256; off <<= 1) {
        int t = (i >= off) ? sh[i - off] : 0;
        __syncthreads();
        sh[i] += t;
        __syncthreads();
    }
    if (i < nb) boff[i] = sh[i] - v;
    if (i == 255) rowptr[n] = sh[255];
}

__global__ __launch_bounds__(256) void gin_scan(const int* __restrict__ deg,
                                                const int* __restrict__ boff,
                                                int* __restrict__ rowptr,
                                                int* __restrict__ cursor, int n) {
    __shared__ int sh[256];
    int i = blockIdx.x * 256 + threadIdx.x;
    int v = (i < n) ? deg[i] : 0;
    sh[threadIdx.x] = v;
    __syncthreads();
    for (int off = 1; off < 256; off <<= 1) {
        int t = (threadIdx.x >= off) ? sh[threadIdx.x - off] : 0;
        __syncthreads();
        sh[threadIdx.x] += t;
        __syncthreads();
    }
    if (i < n) {
        int ex = boff[blockIdx.x] + sh[threadIdx.x] - v;
        rowptr[i] = ex;
        cursor[i] = ex;
    }
}

__global__ __launch_bounds__(256) void gin_fill(const int* __restrict__ src,
                                                const int* __restrict__ dst,
                                                int* __restrict__ cursor,
                                                int* __restrict__ csr_src, int nedges) {
    int e = blockIdx.x * 256 + threadIdx.x;
    if (e < nedges) {
        int pos = atomicAdd(&cursor[dst[e]], 1);
        csr_src[pos] = src[e];
    }
}

// ---------------- gather (bf16): hb[i] = bf16( x[i] + sum_e xb[csr_src[e]] ) ----------------
// one wave per node; lane owns 4B (2 bf16) of the 256B row; 8-deep MLP unroll
__global__ __launch_bounds__(256) void gin_gather_bf(const float* __restrict__ x,
                                                     const ushort* __restrict__ xb,
                                                     const int* __restrict__ rowptr,
                                                     const int* __restrict__ csr_src,
                                                     ushort* __restrict__ hb, int nnodes) {
    int wave = blockIdx.x * 4 + (threadIdx.x >> 6);
    int lane = threadIdx.x & 63;
    if (wave >= nnodes) return;

    int beg = rowptr[wave];
    int end = rowptr[wave + 1];

    float2 acc = *(const float2*)&x[(size_t)wave * D + lane * 2];  // self term fp32 (eps=0)
    const unsigned* xbu = (const unsigned*)xb;  // 1 uint = 2 bf16

    int e = beg;
    for (; e + 8 <= end; e += 8) {
        int s0 = csr_src[e],     s1 = csr_src[e + 1];
        int s2 = csr_src[e + 2], s3 = csr_src[e + 3];
        int s4 = csr_src[e + 4], s5 = csr_src[e + 5];
        int s6 = csr_src[e + 6], s7 = csr_src[e + 7];
        unsigned v0 = xbu[(size_t)s0 * 64 + lane];
        unsigned v1 = xbu[(size_t)s1 * 64 + lane];
        unsigned v2 = xbu[(size_t)s2 * 64 + lane];
        unsigned v3 = xbu[(size_t)s3 * 64 + lane];
        unsigned v4 = xbu[(size_t)s4 * 64 + lane];
        unsigned v5 = xbu[(size_t)s5 * 64 + lane];
        unsigned v6 = xbu[(size_t)s6 * 64 + lane];
        unsigned v7 = xbu[(size_t)s7 * 64 + lane];
        acc.x += ((bflo(v0) + bflo(v1)) + (bflo(v2) + bflo(v3)))
               + ((bflo(v4) + bflo(v5)) + (bflo(v6) + bflo(v7)));
        acc.y += ((bfhi(v0) + bfhi(v1)) + (bfhi(v2) + bfhi(v3)))
               + ((bfhi(v4) + bfhi(v5)) + (bfhi(v6) + bfhi(v7)));
    }
    if (e + 4 <= end) {
        int s0 = csr_src[e],     s1 = csr_src[e + 1];
        int s2 = csr_src[e + 2], s3 = csr_src[e + 3];
        unsigned v0 = xbu[(size_t)s0 * 64 + lane];
        unsigned v1 = xbu[(size_t)s1 * 64 + lane];
        unsigned v2 = xbu[(size_t)s2 * 64 + lane];
        unsigned v3 = xbu[(size_t)s3 * 64 + lane];
        acc.x += (bflo(v0) + bflo(v1)) + (bflo(v2) + bflo(v3));
        acc.y += (bfhi(v0) + bfhi(v1)) + (bfhi(v2) + bfhi(v3));
        e += 4;
    }
    for (; e < end; ++e) {
        unsigned v = xbu[(size_t)csr_src[e] * 64 + lane];
        acc.x += bflo(v);
        acc.y += bfhi(v);
    }
    unsigned o = (unsigned)f2bf(acc.x) | ((unsigned)f2bf(acc.y) << 16);
    ((unsigned*)hb)[(size_t)wave * 64 + lane] = o;
}

// ---------------- MFMA GEMM: out = hb @ W^T + b (bf16 in, fp32 out) ----------------
// block = 256 thr = 4 waves (2x2), BM=64, N=128, K=128; 16x16x32 bf16 MFMA
__global__ __launch_bounds__(256) void gin_gemm_mfma(const ushort* __restrict__ hb,
                                                     const float* __restrict__ W,
                                                     const float* __restrict__ bias,
                                                     float* __restrict__ out, int nrows) {
    __shared__ ushort Wl[D * LDW];   // Wl[o][k] = bf16(W[o][k]) — B operand, k contiguous
    __shared__ ushort Al[64 * LDW];  // Al[m][k] = hb tile

    int tid = threadIdx.x;

    for (int i = tid; i < D * D / 4; i += 256) {
        float4 v = ((const float4*)W)[i];
        int row = i >> 5;
        int col = (i & 31) * 4;
        ushort4 o;
        o.x = f2bf(v.x); o.y = f2bf(v.y); o.z = f2bf(v.z); o.w = f2bf(v.w);
        *(ushort4*)&Wl[row * LDW + col] = o;
    }

    int base = blockIdx.x * 64;
    for (int j = tid; j < 1024; j += 256) {
        int row = j >> 4;
        int col = (j & 15) * 8;
        uint4 v = make_uint4(0, 0, 0, 0);
        if (base + row < nrows) v = *(const uint4*)&hb[(size_t)(base + row) * D + col];
        *(uint4*)&Al[row * LDW + col] = v;
    }
    __syncthreads();

    int w = tid >> 6, l = tid & 63;
    int wr = w >> 1, wc = w & 1;     // 2x2 wave grid: 32 rows x 64 cols per wave
    int lr = l & 15, hi = l >> 4;

    f32x4 acc[2][4];
#pragma unroll
    for (int m = 0; m < 2; m++)
#pragma unroll
        for (int t = 0; t < 4; t++) acc[m][t] = (f32x4)0.0f;

#pragma unroll
    for (int ks = 0; ks < 4; ks++) {
        int kof = ks * 32 + hi * 8;
        bf16x8 a0 = *(bf16x8*)&Al[(wr * 32 + lr) * LDW + kof];
        bf16x8 a1 = *(bf16x8*)&Al[(wr * 32 + 16 + lr) * LDW + kof];
#pragma unroll
        for (int t = 0; t < 4; t++) {
            bf16x8 bm = *(bf16x8*)&Wl[(wc * 64 + t * 16 + lr) * LDW + kof];
            acc[0][t] = __builtin_amdgcn_mfma_f32_16x16x32_bf16(a0, bm, acc[0][t], 0, 0, 0);
            acc[1][t] = __builtin_amdgcn_mfma_f32_16x16x32_bf16(a1, bm, acc[1][t], 0, 0, 0);
        }
    }

    // C/D layout (m89-verified): col = lane&15, row = (lane>>4)*4 + reg
#pragma unroll
    for (int m = 0; m < 2; m++) {
#pragma unroll
        for (int t = 0; t < 4; t++) {
            int col = wc * 64 + t * 16 + lr;
            float bv = bias[col];
#pragma unroll
            for (int r = 0; r < 4; r++) {
                int row = base + wr * 32 + m * 16 + hi * 4 + r;
                if (row < nrows) out[(size_t)row * D + col] = acc[m][t][r] + bv;
            }
        }
    }
}

extern "C" void kernel_launch(void* const* d_in, const int* in_sizes, int n_in,
                              void* d_out, int out_size, void* d_ws, size_t ws_size,
                              hipStream_t stream) {
    const float* x  = (const float*)d_in[0];
    const int*   ei = (const int*)d_in[1];
    const float* W  = (const float*)d_in[2];
    const float* bb = (const float*)d_in[3];
    float* out = (float*)d_out;

    int nnodes = in_sizes[0] / D;
    int nedges = in_sizes[1] / 2;
    const int* src = ei;
    const int* dst = ei + nedges;

    int nb = (nnodes + 255) / 256;
    int npad = nb * 256;

    // workspace layout
    char* p = (char*)d_ws;
    int* deg     = (int*)p;  p += (size_t)npad * 4;
    int* rowptr  = (int*)p;  p += (size_t)(nnodes + 1) * 4;
    int* cursor  = (int*)p;  p += (size_t)npad * 4;
    int* bsum    = (int*)p;  p += 256 * 4;
    int* boff    = (int*)p;  p += 256 * 4;
    int* csr_src = (int*)p;  p += (size_t)nedges * 4;
    p = (char*)(((uintptr_t)p + 15) & ~(uintptr_t)15);
    ushort* xb = (ushort*)p; p += (size_t)nnodes * D * 2;
    ushort* hb = (ushort*)p; p += (size_t)nnodes * D * 2;

    int eb = (nedges + 255) / 256;
    int n4 = nnodes * (D / 4);

    // prep: zero deg + cvt x->bf16 (replaces pathological hipMemsetAsync fill, R3: 41 µs for 196 KB)
    gin_prep<<<2048, 256, 0, stream>>>(x, xb, n4, deg, npad / 4);

    gin_hist<<<eb, 256, 0, stream>>>(dst, deg, nedges);
    gin_bsum<<<nb, 256, 0, stream>>>(deg, bsum, nnodes);
    gin_bscan<<<1, 256, 0, stream>>>(bsum, boff, rowptr, nb, nnodes);
    gin_scan<<<nb, 256, 0, stream>>>(deg, boff, rowptr, cursor, nnodes);
    gin_fill<<<eb, 256, 0, stream>>>(src, dst, cursor, csr_src, nedges);

    int gb = (nnodes + 3) / 4;  // 4 waves per block, 1 node per wave
    gin_gather_bf<<<gb, 256, 0, stream>>>(x, xb, rowptr, csr_src, hb, nnodes);

    int gemb = (nnodes + 63) / 64;
    gin_gemm_mfma<<<gemb, 256, 0, stream>>>(hb, W, bb, out, nnodes);
}